// Round 8
// baseline (263.830 us; speedup 1.0000x reference)
//
#include <hip/hip_runtime.h>
#include <hip/hip_bf16.h>
#include <cstdint>
#include <cstddef>

typedef __hip_bfloat16 bf16;
typedef __attribute__((ext_vector_type(8))) short short8;
typedef __attribute__((ext_vector_type(4))) short short4v;
typedef __attribute__((ext_vector_type(4))) float floatx4;

// Problem dims (all tensors float32; gates bf16 in LDS only)
#define BB 8
#define SS 4096
#define DIN 256
#define DH 512
#define NCH 256
#define CHUNK 16       // NCH*CHUNK == SS

__device__ __forceinline__ float b2f(bf16 v) { return __bfloat162float(v); }
__device__ __forceinline__ float frcp(float x) { return __builtin_amdgcn_rcpf(x); }

// ---------------- kernel 0: prep = W transpose (LDS-tiled) + x convert -------
// blocks [0, nconv): convert X (f32 -> bf16), 1024 elems/block
// blocks [nconv, nconv+512): transpose Wg[256][512] -> Wt[(g*512+h)][256] bf16
__global__ __launch_bounds__(256) void prep(
    const float* __restrict__ X, bf16* __restrict__ Xb,
    const float* __restrict__ Wi, const float* __restrict__ Wf,
    const float* __restrict__ Wo, const float* __restrict__ Wz,
    bf16* __restrict__ Wt, int nconv)
{
    __shared__ float tile[32][33];
    const int tid = threadIdx.x;
    if ((int)blockIdx.x < nconv) {
        const int idx = blockIdx.x * 256 + tid;
        float4 v = ((const float4*)X)[idx];
        bf16 o[4] = {__float2bfloat16(v.x), __float2bfloat16(v.y),
                     __float2bfloat16(v.z), __float2bfloat16(v.w)};
        ((short4v*)Xb)[idx] = *(const short4v*)o;
        return;
    }
    const int beta = blockIdx.x - nconv;        // 0..511
    const int g   = beta >> 7;
    const int rem = beta & 127;
    const int k0  = (rem >> 4) * 32;
    const int h0  = (rem & 15) * 32;
    const float* W = (g == 0) ? Wi : (g == 1) ? Wf : (g == 2) ? Wo : Wz;

    {   // coalesced read: 32 k-rows x 32 h-cols
        const int r = tid >> 5;          // 0..7
        const int c = tid & 31;          // 0..31
#pragma unroll
        for (int j = 0; j < 4; j++)
            tile[r + j * 8][c] = W[(size_t)(k0 + r + j * 8) * DH + h0 + c];
    }
    __syncthreads();
    {   // coalesced write: 32 h-rows x 32 k-cols of Wt
        const int kw = tid & 31;
        const int hw = tid >> 5;         // 0..7
#pragma unroll
        for (int j = 0; j < 4; j++) {
            const int h = hw + j * 8;
            Wt[(size_t)(g * 512 + h0 + h) * DIN + k0 + kw] =
                __float2bfloat16(tile[kw][h]);
        }
    }
}

// ---------------- global->LDS DMA helper -------------------------------------
__device__ __forceinline__ void load16_lds(const bf16* g, short* l)
{
    __builtin_amdgcn_global_load_lds(
        (const __attribute__((address_space(1))) unsigned int*)g,
        (__attribute__((address_space(3))) unsigned int*)l,
        16, 0, 0);
}

// ---------------- kernel 1: GEMM (i,f,z) + activation + chunk carries --------
// Block: 64 m x 64 h x 3 gates. Waves 0,1 compute i,f; wave 3 computes z;
// wave 2 idles MFMA (helps staging + carries). No plane output — only
// per-chunk-of-16 affine carries (A, Bc, Bn).
__global__ __launch_bounds__(256) void gemm_carry(
    const bf16* __restrict__ Xb, const bf16* __restrict__ Wt,
    const float* __restrict__ bi, const float* __restrict__ bfv,
    const float* __restrict__ bz,
    float* __restrict__ Aa, float* __restrict__ Bca, float* __restrict__ Bna,
    int nb)
{
    __shared__ __align__(16) short As[64 * 32];        // 4 KB
    __shared__ __align__(16) short Bs[3 * 64 * 32];    // 12 KB: 0=i,1=f,2=z
    __shared__ __align__(16) bf16  Gb[3 * 64 * 64];    // 24 KB: 0=i,1=f,2=z

    const int tid  = threadIdx.x;
    const int m0   = blockIdx.x * 64;
    const int h0   = blockIdx.y * 64;
    const int wave = tid >> 6, lane = tid & 63;
    const int l15  = lane & 15;
    const int q    = lane >> 4;
    const int gslice = (wave == 3) ? 2 : wave;   // compute waves: 0,1,3

    floatx4 acc[4][4];
#pragma unroll
    for (int i = 0; i < 4; i++)
#pragma unroll
        for (int j = 0; j < 4; j++) acc[i][j] = (floatx4){0.f, 0.f, 0.f, 0.f};

    const int rr = tid >> 2;
    const int cc = (tid & 3) * 8;
    const bf16* agp  = Xb + (size_t)(m0 + rr) * DIN + cc;
    const bf16* bgpi = Wt + (size_t)(0 * 512 + h0 + rr) * DIN + cc;
    const bf16* bgpf = Wt + (size_t)(1 * 512 + h0 + rr) * DIN + cc;
    const bf16* bgpz = Wt + (size_t)(3 * 512 + h0 + rr) * DIN + cc;

    for (int k0 = 0; k0 < DIN; k0 += 32) {
        load16_lds(agp  + k0, &As[tid * 8]);
        load16_lds(bgpi + k0, &Bs[0 * 2048 + tid * 8]);
        load16_lds(bgpf + k0, &Bs[1 * 2048 + tid * 8]);
        load16_lds(bgpz + k0, &Bs[2 * 2048 + tid * 8]);
        __syncthreads();

        if (wave != 2) {
            short8 af[4], bfr[4];
#pragma unroll
            for (int ti = 0; ti < 4; ti++)
                af[ti] = *(const short8*)&As[(ti * 16 + l15) * 32 + q * 8];
#pragma unroll
            for (int tj = 0; tj < 4; tj++)
                bfr[tj] = *(const short8*)&Bs[gslice * 2048 + (tj * 16 + l15) * 32 + q * 8];
#pragma unroll
            for (int ti = 0; ti < 4; ti++)
#pragma unroll
                for (int tj = 0; tj < 4; tj++)
                    acc[ti][tj] = __builtin_amdgcn_mfma_f32_16x16x32_bf16(
                        af[ti], bfr[tj], acc[ti][tj], 0, 0, 0);
        }
        __syncthreads();
    }

    if (wave != 2) {
        const float* bias = (wave == 0) ? bi : (wave == 1) ? bfv : bz;
        bf16* gb = &Gb[gslice * 4096];
#pragma unroll
        for (int ti = 0; ti < 4; ti++) {
#pragma unroll
            for (int tj = 0; tj < 4; tj++) {
                const int h = tj * 16 + l15;
                const float bsv = bias[h0 + h];
#pragma unroll
                for (int r = 0; r < 4; r++) {
                    const int s = ti * 16 + q * 4 + r;
                    const float v = acc[ti][tj][r] + bsv;
                    float a;
                    if (wave == 0 || wave == 1)
                        a = __expf(fminf(fmaxf(v, -20.f), 0.f));      // exp(clip)
                    else
                        a = 1.f - 2.f * frcp(__expf(2.f * v) + 1.f);  // tanh
                    gb[s * 64 + h] = __float2bfloat16(a);
                }
            }
        }
    }
    __syncthreads();

    // chunk carries: 256 threads = 64 h x 4 sub-chunks of 16
    {
        const int hh  = tid & 63;
        const int sub = tid >> 6;
        float A = 1.f, Bc = 0.f, Bn = 0.f;
#pragma unroll
        for (int s = 0; s < CHUNK; s++) {
            const int sl = sub * CHUNK + s;
            const float iv = b2f(Gb[0 * 4096 + sl * 64 + hh]);
            const float f  = b2f(Gb[1 * 4096 + sl * 64 + hh]);
            const float zv = b2f(Gb[2 * 4096 + sl * 64 + hh]);
            Bc = fmaf(f, Bc, iv * zv);
            Bn = fmaf(f, Bn, iv);
            A *= f;
        }
        const int b  = m0 >> 12;             // batch (SS = 4096)
        const int s0 = m0 & (SS - 1);
        const int ch = (s0 >> 4) + sub;
        const size_t cidx = ((size_t)ch * nb + b) * DH + h0 + hh;
        Aa[cidx] = A; Bca[cidx] = Bc; Bna[cidx] = Bn;
    }
}

// ---------------- kernel 2: sequential scan over chunk carries ---------------
__global__ __launch_bounds__(256) void scan_chunks(
    const float* __restrict__ Aa, const float* __restrict__ Bca,
    const float* __restrict__ Bna,
    float* __restrict__ Cs, float* __restrict__ Ns, int nb)
{
    const int t = blockIdx.x * 256 + threadIdx.x;   // b*512+h chain
    float c = 0.f, n = 1.f;
    for (int ch = 0; ch < NCH; ch++) {
        const size_t cidx = (size_t)ch * (nb * DH) + t;
        Cs[cidx] = c; Ns[cidx] = n;                 // state BEFORE chunk ch
        const float A = Aa[cidx];
        c = fmaf(A, c, Bca[cidx]);
        n = fmaf(A, n, Bna[cidx]);
    }
}

// ---------------- kernel 3: GEMM (all 4 gates) + recurrence + emit h ---------
// Recomputes gates into LDS (no plane reads), then each thread replays its
// 16-step sub-chunk from Cs/Ns and writes h (f32) directly.
__global__ __launch_bounds__(256) void gemm_emit(
    const bf16* __restrict__ Xb, const bf16* __restrict__ Wt,
    const float* __restrict__ bi, const float* __restrict__ bfv,
    const float* __restrict__ bo, const float* __restrict__ bz,
    const float* __restrict__ Cs, const float* __restrict__ Ns,
    float* __restrict__ out, int nb)
{
    __shared__ __align__(16) short As[64 * 32];        // 4 KB
    __shared__ __align__(16) short Bs[4 * 64 * 32];    // 16 KB
    __shared__ __align__(16) bf16  Gb[4 * 64 * 64];    // 32 KB  [g][s][h]

    const int tid  = threadIdx.x;
    const int m0   = blockIdx.x * 64;
    const int h0   = blockIdx.y * 64;
    const int wave = tid >> 6, lane = tid & 63;
    const int l15  = lane & 15;
    const int q    = lane >> 4;

    floatx4 acc[4][4];
#pragma unroll
    for (int i = 0; i < 4; i++)
#pragma unroll
        for (int j = 0; j < 4; j++) acc[i][j] = (floatx4){0.f, 0.f, 0.f, 0.f};

    const int rr = tid >> 2;
    const int cc = (tid & 3) * 8;
    const bf16* agp  = Xb + (size_t)(m0 + rr) * DIN + cc;
    const bf16* bgp0 = Wt + (size_t)(0 * 512 + h0 + rr) * DIN + cc;
    const bf16* bgp1 = Wt + (size_t)(1 * 512 + h0 + rr) * DIN + cc;
    const bf16* bgp2 = Wt + (size_t)(2 * 512 + h0 + rr) * DIN + cc;
    const bf16* bgp3 = Wt + (size_t)(3 * 512 + h0 + rr) * DIN + cc;

    for (int k0 = 0; k0 < DIN; k0 += 32) {
        load16_lds(agp  + k0, &As[tid * 8]);
        load16_lds(bgp0 + k0, &Bs[0 * 2048 + tid * 8]);
        load16_lds(bgp1 + k0, &Bs[1 * 2048 + tid * 8]);
        load16_lds(bgp2 + k0, &Bs[2 * 2048 + tid * 8]);
        load16_lds(bgp3 + k0, &Bs[3 * 2048 + tid * 8]);
        __syncthreads();

        short8 af[4], bfr[4];
#pragma unroll
        for (int ti = 0; ti < 4; ti++)
            af[ti] = *(const short8*)&As[(ti * 16 + l15) * 32 + q * 8];
#pragma unroll
        for (int tj = 0; tj < 4; tj++)
            bfr[tj] = *(const short8*)&Bs[wave * 2048 + (tj * 16 + l15) * 32 + q * 8];
#pragma unroll
        for (int ti = 0; ti < 4; ti++)
#pragma unroll
            for (int tj = 0; tj < 4; tj++)
                acc[ti][tj] = __builtin_amdgcn_mfma_f32_16x16x32_bf16(
                    af[ti], bfr[tj], acc[ti][tj], 0, 0, 0);
        __syncthreads();
    }

    // activation -> Gb (gate = wave)
    const float* bias = (wave == 0) ? bi : (wave == 1) ? bfv
                      : (wave == 2) ? bo : bz;
    bf16* gb = &Gb[wave * 4096];
#pragma unroll
    for (int ti = 0; ti < 4; ti++) {
#pragma unroll
        for (int tj = 0; tj < 4; tj++) {
            const int h = tj * 16 + l15;
            const float bsv = bias[h0 + h];
#pragma unroll
            for (int r = 0; r < 4; r++) {
                const int s = ti * 16 + q * 4 + r;
                const float v = acc[ti][tj][r] + bsv;
                float a;
                if (wave == 0 || wave == 1)
                    a = __expf(fminf(fmaxf(v, -20.f), 0.f));      // exp(clip)
                else if (wave == 2)
                    a = frcp(1.f + __expf(-v));                   // sigmoid
                else
                    a = 1.f - 2.f * frcp(__expf(2.f * v) + 1.f);  // tanh
                gb[s * 64 + h] = __float2bfloat16(a);
            }
        }
    }
    __syncthreads();

    // recurrence replay: thread = (h, sub-chunk of 16); write h to out
    {
        const int hh  = tid & 63;
        const int sub = tid >> 6;
        const int b   = m0 >> 12;
        const int s0  = m0 & (SS - 1);
        const int ch  = (s0 >> 4) + sub;
        const size_t cidx = ((size_t)ch * nb + b) * DH + h0 + hh;
        float c = Cs[cidx], n = Ns[cidx];
#pragma unroll
        for (int s = 0; s < CHUNK; s++) {
            const int sl = sub * CHUNK + s;
            const float iv = b2f(Gb[0 * 4096 + sl * 64 + hh]);
            const float f  = b2f(Gb[1 * 4096 + sl * 64 + hh]);
            const float ov = b2f(Gb[2 * 4096 + sl * 64 + hh]);
            const float zv = b2f(Gb[3 * 4096 + sl * 64 + hh]);
            c = fmaf(f, c, iv * zv);
            n = fmaf(f, n, iv);
            out[(size_t)(m0 + sl) * DH + h0 + hh] = ov * c * frcp(n + 1e-6f);
        }
    }
}

// ---------------- launch -----------------------------------------------------
extern "C" void kernel_launch(void* const* d_in, const int* in_sizes, int n_in,
                              void* d_out, int out_size, void* d_ws, size_t ws_size,
                              hipStream_t stream)
{
    const float* x   = (const float*)d_in[0];
    const float* Wi  = (const float*)d_in[1];
    const float* bi  = (const float*)d_in[2];
    const float* Wf  = (const float*)d_in[3];
    const float* bfv = (const float*)d_in[4];
    const float* Wo  = (const float*)d_in[5];
    const float* bo  = (const float*)d_in[6];
    const float* Wz  = (const float*)d_in[7];
    const float* bz  = (const float*)d_in[8];
    float* out = (float*)d_out;

    // ws-adaptive (footprint at nb=8 is ~39 MB)
    int nb = BB;
    while (nb > 1) {
        size_t need = (1u << 20)                         // Wt
                    + (size_t)nb * SS * DIN * 2          // Xb
                    + 5 * (size_t)NCH * nb * DH * 4;     // Aa,Bca,Bna,Cs,Ns
        if (need <= ws_size) break;
        nb >>= 1;
    }

    bf16* Wt = (bf16*)d_ws;
    bf16* Xb = (bf16*)((char*)d_ws + (1u << 20));
    float* Aa  = (float*)(Xb + (size_t)nb * SS * DIN);
    float* Bca = Aa  + (size_t)NCH * nb * DH;
    float* Bna = Bca + (size_t)NCH * nb * DH;
    float* Cs  = Bna + (size_t)NCH * nb * DH;
    float* Ns  = Cs  + (size_t)NCH * nb * DH;

    for (int b0 = 0; b0 < BB; b0 += nb) {
        const float* Xsrc = x   + (size_t)b0 * SS * DIN;
        float*       Ob   = out + (size_t)b0 * SS * DH;
        const int nconv = nb * 1024;                    // convert blocks
        const int ntr   = (b0 == 0) ? 512 : 0;          // transpose once
        prep<<<nconv + ntr, 256, 0, stream>>>(
            Xsrc, Xb, Wi, Wf, Wo, Wz, Wt, nconv);
        gemm_carry<<<dim3(nb * SS / 64, DH / 64), 256, 0, stream>>>(
            Xb, Wt, bi, bfv, bz, Aa, Bca, Bna, nb);
        scan_chunks<<<2 * nb, 256, 0, stream>>>(Aa, Bca, Bna, Cs, Ns, nb);
        gemm_emit<<<dim3(nb * SS / 64, DH / 64), 256, 0, stream>>>(
            Xb, Wt, bi, bfv, bo, bz, Cs, Ns, Ob, nb);
    }
}